// Round 7
// baseline (53.171 us; speedup 1.0000x reference)
//
#include <hip/hip_runtime.h>
#include <math.h>

#define LQ 256
#define MEML 256
#define LK 512
#define BB 4
#define NH 8
#define DH 16
#define DM 128

constexpr float INV2PI = 0.15915494309189535f;

// ---------------------------------------------------------------------------
// Projection + sincos tables, pre-scaled by paramR[h]/(2*pi):
//   q-side packed rows: qP[(i*32+bh)*48 + {d, 16+d, 32+d}] = {v, sin, cos}
//     (8192 rows x 48 floats, row base 192B-aligned)
//   k-side transposed:  kT*[(bh*16+d)*512 + j]   (coalesced along j)
// 4 input rows per block (one i or j), 128 threads (one per output column o).
// ---------------------------------------------------------------------------
__global__ __launch_bounds__(128) void proj_kernel(
    const float* __restrict__ hh, const float* __restrict__ mems,
    const float* __restrict__ Wq, const float* __restrict__ Wk,
    const float* __restrict__ paramR,
    float* __restrict__ qP,
    float* __restrict__ kTv, float* __restrict__ kTs, float* __restrict__ kTc)
{
    __shared__ float x[4 * 128];
    const int blk = blockIdx.x;
    const int t = threadIdx.x;
    const bool isQ = (blk < 256);                 // 256 q-blocks, 512 k-blocks
    const int row0 = isQ ? blk * 4 : (blk - 256) * 4;
    const float* __restrict__ W = isQ ? Wq : Wk;

    for (int r = 0; r < 4; ++r) {
        const int row = row0 + r;
        const float* src = isQ ? (hh + row * DM)
                               : ((row < MEML * BB) ? (mems + row * DM)
                                                    : (hh + (row - MEML * BB) * DM));
        x[r * 128 + t] = src[t];
    }
    __syncthreads();

    float acc[4] = {0, 0, 0, 0};
    const float* wrow = W + t * DM;
    for (int k = 0; k < DM; k += 4) {
        const float4 w = *(const float4*)(wrow + k);
        #pragma unroll
        for (int r = 0; r < 4; ++r) {
            acc[r] += x[r * 128 + k + 0] * w.x + x[r * 128 + k + 1] * w.y
                    + x[r * 128 + k + 2] * w.z + x[r * 128 + k + 3] * w.w;
        }
    }
    const int h = t >> 4, d = t & 15;
    const float rs = paramR[h] * INV2PI;
    #pragma unroll
    for (int r = 0; r < 4; ++r) {
        const float v = acc[r] * rs;
        const float sn = __builtin_amdgcn_sinf(v);    // sin(2pi*v)
        const float cs = __builtin_amdgcn_cosf(v);    // cos(2pi*v)
        const int row = row0 + r;
        const int b = row & 3;
        if (isQ) {
            const int i = row >> 2;
            float* qp = qP + (i * 32 + b * 8 + h) * 48;
            qp[d] = v; qp[16 + d] = sn; qp[32 + d] = cs;
        } else {
            const int j = row >> 2;
            const int idx = ((b * 8 + h) * 16 + d) * LK + j;
            kTv[idx] = v; kTs[idx] = sn; kTc[idx] = cs;
        }
    }
}

// ---------------------------------------------------------------------------
// Score. wave w = t>>6 (NO readfirstlane: address stays "divergent" so the
// compiler emits VECTOR loads; all lanes hit the same line -> 1 transaction,
// pipelined via vmcnt across unrolled ii's). lane -> j; k-triple in 48 VGPRs
// loaded once coalesced, reused over 16 i. Per-ii result goes straight to the
// LDS transpose tile (no long-lived r[16]); one barrier; coalesced stores.
// ---------------------------------------------------------------------------
#define TSTRIDE 69
__global__ __launch_bounds__(512) void score_kernel(
    const float* __restrict__ qP,
    const float* __restrict__ kTv, const float* __restrict__ kTs,
    const float* __restrict__ kTc,
    float* __restrict__ out)
{
    __shared__ float tile[16 * 8 * TSTRIDE];      // 35.3 KB
    const int t = threadIdx.x;
    const int lane = t & 63;
    const int w = t >> 6;                         // 0..7 (divergent to compiler)
    const int b = blockIdx.z;                     // 0..3
    const int bh = b * 8 + w;
    const int j = blockIdx.y * 64 + lane;
    const int i0 = blockIdx.x * 16;

    constexpr float i2 = INV2PI * INV2PI;
    constexpr float i4 = i2 * i2;
    constexpr float i8 = i4 * i4;
    constexpr float C16 = i8 * i8;                // (2pi)^-16
    constexpr float EPS = 4.0e-4f;                // revolutions

    float kd[16], ks[16], kc[16];
    #pragma unroll
    for (int d = 0; d < 16; ++d) {
        const int off = (bh * 16 + d) * LK + j;   // lanes consecutive: coalesced
        kd[d] = kTv[off];
        ks[d] = kTs[off];
        kc[d] = kTc[off];
    }

    #pragma unroll
    for (int ii = 0; ii < 16; ++ii) {
        const float* __restrict__ qp = qP + ((i0 + ii) * 32 + bh) * 48;
        float qd[16], qs_[16], qc_[16];
        #pragma unroll
        for (int d = 0; d < 16; d += 4) {
            const float4 a = *(const float4*)(qp + d);
            const float4 s = *(const float4*)(qp + 16 + d);
            const float4 c = *(const float4*)(qp + 32 + d);
            qd[d]  = a.x; qd[d+1]  = a.y; qd[d+2]  = a.z; qd[d+3]  = a.w;
            qs_[d] = s.x; qs_[d+1] = s.y; qs_[d+2] = s.z; qs_[d+3] = s.w;
            qc_[d] = c.x; qc_[d+1] = c.y; qc_[d+2] = c.z; qc_[d+3] = c.w;
        }
        float pn0 = 1.f, pd0 = 1.f, pn1 = 1.f, pd1 = 1.f;
        #pragma unroll
        for (int d = 0; d < 16; ++d) {
            const float dl  = qd[d] - kd[d];
            const float num = qs_[d] * kc[d] - qc_[d] * ks[d];
            const bool  g   = __builtin_fabsf(dl) > EPS;
            const float nn = g ? num : 1.0f;
            const float dd = g ? dl : INV2PI;
            if (d < 8) { pn0 *= nn; pd0 *= dd; }
            else       { pn1 *= nn; pd1 *= dd; }
        }
        const float r = __builtin_fabsf(pn0 * __builtin_amdgcn_rcpf(pd0)
                                      * pn1 * __builtin_amdgcn_rcpf(pd1)) * C16;
        tile[(ii * 8 + w) * TSTRIDE + lane] = r;
    }
    __syncthreads();

    const int j0 = blockIdx.y * 64;
    #pragma unroll
    for (int rep = 0; rep < 16; ++rep) {
        const int idx = rep * 512 + t;
        const int bl = idx & 7;
        const int jL = (idx >> 3) & 63;
        const int ii = idx >> 9;
        out[((i0 + ii) * LK + j0 + jL) * 32 + b * 8 + bl] =
            tile[(ii * 8 + bl) * TSTRIDE + jL];
    }
}

extern "C" void kernel_launch(void* const* d_in, const int* in_sizes, int n_in,
                              void* d_out, int out_size, void* d_ws, size_t ws_size,
                              hipStream_t stream) {
    const float* hh     = (const float*)d_in[0];
    const float* mems   = (const float*)d_in[1];
    const float* Wq     = (const float*)d_in[2];
    const float* Wk     = (const float*)d_in[3];
    const float* paramR = (const float*)d_in[4];
    float* out = (float*)d_out;

    float* qP  = (float*)d_ws;                 // 8192 rows x 48 = 393216 floats
    float* kTv = qP  + LQ * BB * NH * 48;      // 262144 floats each
    float* kTs = kTv + LK * BB * DM;
    float* kTc = kTs + LK * BB * DM;

    proj_kernel<<<768, 128, 0, stream>>>(hh, mems, Wq, Wk, paramR,
                                         qP, kTv, kTs, kTc);
    score_kernel<<<dim3(16, 8, 4), 512, 0, stream>>>(qP, kTv, kTs, kTc, out);
}

// Round 8
// 38.415 us; speedup vs baseline: 1.3841x; 1.3841x over previous
//
#include <hip/hip_runtime.h>
#include <math.h>

#define LQ 256
#define MEML 256
#define LK 512
#define BB 4
#define NH 8
#define DM 128

constexpr float INV2PI = 0.15915494309189535f;

// ---------------------------------------------------------------------------
// Projection, pre-scaled by paramR[h]/(2*pi). Values only (no sincos tables):
//   qs[(i*4+b)*128 + h*16+d]                        (row-major, float4-able)
//   ksT[((d>>2)*512 + j)*128 + (b*8+h)*4 + (d&3)]   (score k-loads 1KB/wave)
// 2 input rows per block -> 1536 blocks (3 waves/SIMD). float4 LDS reads.
// ---------------------------------------------------------------------------
__global__ __launch_bounds__(128) void proj_kernel(
    const float* __restrict__ hh, const float* __restrict__ mems,
    const float* __restrict__ Wq, const float* __restrict__ Wk,
    const float* __restrict__ paramR,
    float* __restrict__ qs, float* __restrict__ ksT)
{
    __shared__ float x[2 * 128];
    const int blk = blockIdx.x;
    const int t = threadIdx.x;
    const bool isQ = (blk < 512);                 // 512 q-blocks, 1024 k-blocks
    const int row0 = isQ ? blk * 2 : (blk - 512) * 2;
    const float* __restrict__ W = isQ ? Wq : Wk;

    #pragma unroll
    for (int r = 0; r < 2; ++r) {
        const int row = row0 + r;
        const float* src = isQ ? (hh + row * DM)
                               : ((row < MEML * BB) ? (mems + row * DM)
                                                    : (hh + (row - MEML * BB) * DM));
        x[r * 128 + t] = src[t];
    }
    __syncthreads();

    float acc0 = 0.f, acc1 = 0.f;
    const float* wrow = W + t * DM;
    #pragma unroll 8
    for (int k = 0; k < DM; k += 4) {
        const float4 w  = *(const float4*)(wrow + k);
        const float4 x0 = *(const float4*)(&x[k]);
        const float4 x1 = *(const float4*)(&x[128 + k]);
        acc0 += x0.x * w.x + x0.y * w.y + x0.z * w.z + x0.w * w.w;
        acc1 += x1.x * w.x + x1.y * w.y + x1.z * w.z + x1.w * w.w;
    }
    const int h = t >> 4, d = t & 15;
    const float rs = paramR[h] * INV2PI;
    const float v0 = acc0 * rs, v1 = acc1 * rs;
    if (isQ) {
        qs[(row0 + 0) * 128 + t] = v0;
        qs[(row0 + 1) * 128 + t] = v1;
    } else {
        const int j0 = (row0 + 0) >> 2, b0 = (row0 + 0) & 3;
        const int j1 = (row0 + 1) >> 2, b1 = (row0 + 1) & 3;
        ksT[((d >> 2) * LK + j0) * 128 + (b0 * 8 + h) * 4 + (d & 3)] = v0;
        ksT[((d >> 2) * LK + j1) * 128 + (b1 * 8 + h) * 4 + (d & 3)] = v1;
    }
}

// ---------------------------------------------------------------------------
// Score (R2 formulation, occupancy-tuned): per-element v_sin, grouped rcp.
// Thread: bh=t&31, js=t>>5; 1 i per block, 4 m-steps -> 4 outputs/thread.
// State ~56 VGPR; __launch_bounds__(256,8) pins <=64 VGPR -> 8 waves/SIMD.
// ---------------------------------------------------------------------------
__global__ __launch_bounds__(256, 8) void score_kernel(
    const float* __restrict__ qs, const float* __restrict__ ksT,
    float* __restrict__ out)
{
    const int t = threadIdx.x;
    const int bh = t & 31;
    const int js = t >> 5;                        // 0..7
    const int i = blockIdx.x;                     // 256
    const int jbase = blockIdx.y * 32;            // 16 j-tiles of 32

    constexpr float i2 = INV2PI * INV2PI;
    constexpr float i4 = i2 * i2;
    constexpr float i8 = i4 * i4;
    constexpr float C16 = i8 * i8;                // (2pi)^-16
    constexpr float EPS = 2.0e-4f * INV2PI;       // guard threshold (u' units)

    float q[16];
    {
        const float* qp = qs + (i * 32 + bh) * 16;
        #pragma unroll
        for (int d = 0; d < 16; d += 4) {
            const float4 v = *(const float4*)(qp + d);
            q[d] = v.x; q[d + 1] = v.y; q[d + 2] = v.z; q[d + 3] = v.w;
        }
    }

    #pragma unroll
    for (int m = 0; m < 4; ++m) {
        const int j = jbase + m * 8 + js;
        float k[16];
        #pragma unroll
        for (int d4 = 0; d4 < 4; ++d4) {
            const float4 v = *(const float4*)(ksT + (d4 * LK + j) * 128 + bh * 4);
            k[d4 * 4 + 0] = v.x; k[d4 * 4 + 1] = v.y;
            k[d4 * 4 + 2] = v.z; k[d4 * 4 + 3] = v.w;
        }
        float pn0 = 1.f, pd0 = 1.f, pn1 = 1.f, pd1 = 1.f;
        #pragma unroll
        for (int d = 0; d < 16; ++d) {
            const float u = q[d] - k[d];
            const float s = __builtin_amdgcn_sinf(u);   // sin(2pi*u)
            const bool g = __builtin_fabsf(u) > EPS;
            const float nn = g ? s : 1.0f;
            const float dd = g ? u : INV2PI;
            if (d < 8) { pn0 *= nn; pd0 *= dd; }
            else       { pn1 *= nn; pd1 *= dd; }
        }
        const float r0 = pn0 * __builtin_amdgcn_rcpf(pd0);
        const float r1 = pn1 * __builtin_amdgcn_rcpf(pd1);
        out[(i * LK + j) * 32 + bh] = __builtin_fabsf(r0 * r1) * C16;
    }
}

extern "C" void kernel_launch(void* const* d_in, const int* in_sizes, int n_in,
                              void* d_out, int out_size, void* d_ws, size_t ws_size,
                              hipStream_t stream) {
    const float* hh     = (const float*)d_in[0];
    const float* mems   = (const float*)d_in[1];
    const float* Wq     = (const float*)d_in[2];
    const float* Wk     = (const float*)d_in[3];
    const float* paramR = (const float*)d_in[4];
    float* out = (float*)d_out;

    float* qs  = (float*)d_ws;                // 131072 floats
    float* ksT = qs + LQ * BB * DM;           // 262144 floats

    proj_kernel<<<1536, 128, 0, stream>>>(hh, mems, Wq, Wk, paramR, qs, ksT);
    score_kernel<<<dim3(256, 16), 256, 0, stream>>>(qs, ksT, out);
}

// Round 9
// 33.925 us; speedup vs baseline: 1.5673x; 1.1323x over previous
//
#include <hip/hip_runtime.h>
#include <math.h>

#define LQ 256
#define MEML 256
#define LK 512
#define BB 4
#define NH 8
#define DM 128

#define IT 16                 // i-tile per score block
#define QSTRIDE 20            // LDS q row stride (floats): 80B, 16B-aligned

constexpr float INV2PI = 0.15915494309189535f;

// ---------------------------------------------------------------------------
// Projection, pre-scaled by paramR[h]/(2*pi). Values only:
//   qs[(i*32 + b*8 + h)*16 + d]                     (row per (i,bh), 64B)
//   ksT[((d>>2)*512 + j)*128 + (b*8+h)*4 + (d&3)]   (score k-loads 512B/group)
// 2 input rows per block -> 1536 blocks. float4 LDS reads.
// ---------------------------------------------------------------------------
__global__ __launch_bounds__(128) void proj_kernel(
    const float* __restrict__ hh, const float* __restrict__ mems,
    const float* __restrict__ Wq, const float* __restrict__ Wk,
    const float* __restrict__ paramR,
    float* __restrict__ qs, float* __restrict__ ksT)
{
    __shared__ float x[2 * 128];
    const int blk = blockIdx.x;
    const int t = threadIdx.x;
    const bool isQ = (blk < 512);                 // 512 q-blocks, 1024 k-blocks
    const int row0 = isQ ? blk * 2 : (blk - 512) * 2;
    const float* __restrict__ W = isQ ? Wq : Wk;

    #pragma unroll
    for (int r = 0; r < 2; ++r) {
        const int row = row0 + r;
        const float* src = isQ ? (hh + row * DM)
                               : ((row < MEML * BB) ? (mems + row * DM)
                                                    : (hh + (row - MEML * BB) * DM));
        x[r * 128 + t] = src[t];
    }
    __syncthreads();

    float acc0 = 0.f, acc1 = 0.f;
    const float* wrow = W + t * DM;
    #pragma unroll 8
    for (int k = 0; k < DM; k += 4) {
        const float4 w  = *(const float4*)(wrow + k);
        const float4 x0 = *(const float4*)(&x[k]);
        const float4 x1 = *(const float4*)(&x[128 + k]);
        acc0 += x0.x * w.x + x0.y * w.y + x0.z * w.z + x0.w * w.w;
        acc1 += x1.x * w.x + x1.y * w.y + x1.z * w.z + x1.w * w.w;
    }
    const int h = t >> 4, d = t & 15;
    const float rs = paramR[h] * INV2PI;
    const float v0 = acc0 * rs, v1 = acc1 * rs;
    if (isQ) {
        const int i0r = row0 >> 2, b0 = row0 & 3;
        const int i1r = (row0 + 1) >> 2, b1 = (row0 + 1) & 3;
        qs[(i0r * 32 + b0 * 8 + h) * 16 + d] = v0;
        qs[(i1r * 32 + b1 * 8 + h) * 16 + d] = v1;
    } else {
        const int j0 = (row0 + 0) >> 2, b0 = (row0 + 0) & 3;
        const int j1 = (row0 + 1) >> 2, b1 = (row0 + 1) & 3;
        ksT[((d >> 2) * LK + j0) * 128 + (b0 * 8 + h) * 4 + (d & 3)] = v0;
        ksT[((d >> 2) * LK + j1) * 128 + (b1 * 8 + h) * 4 + (d & 3)] = v1;
    }
}

// ---------------------------------------------------------------------------
// Score. Thread owns (j = jbase + t>>5, bh = t&31) for its lifetime:
// k[16] in VGPRs loaded ONCE (coalesced 512B/32-lane group). q staged in
// LDS once per block (16 i x 32 bh x 16 d, stride-20 rows), i-loop reads
// q via ds_read_b128 -> ZERO global loads in the hot loop. Direct stores
// (256B contiguous per wave). Guard via evenness: u2=max(|u|,EPS);
// pn*=sin(u2); pd*=u2  (4 VALU + 1 trans per d).
// ---------------------------------------------------------------------------
__global__ __launch_bounds__(256, 4) void score_kernel(
    const float* __restrict__ qs, const float* __restrict__ ksT,
    float* __restrict__ out)
{
    __shared__ float qt[IT * 32 * QSTRIDE];       // 40 KB
    const int t = threadIdx.x;
    const int bh = t & 31;
    const int js = t >> 5;                        // 0..7
    const int i0 = blockIdx.x * IT;               // 16 i-tiles
    const int j = blockIdx.y * 8 + js;            // 64 j-tiles of 8

    constexpr float i2 = INV2PI * INV2PI;
    constexpr float i4 = i2 * i2;
    constexpr float i8 = i4 * i4;
    constexpr float C16 = i8 * i8;                // (2pi)^-16
    constexpr float EPS = 2.0e-4f * INV2PI;       // 3.18e-5 rev; (EPS)^8 > FLT_MIN

    // stage q-tile: 8192 contiguous floats -> padded LDS rows
    {
        const float* src = qs + i0 * 32 * 16;
        #pragma unroll
        for (int rep = 0; rep < 8; ++rep) {
            const int c4 = rep * 256 + t;         // float4 chunk id, 0..2047
            const int row = c4 >> 2, cc = (c4 & 3) * 4;
            const float4 v = *(const float4*)(src + c4 * 4);
            *(float4*)(&qt[row * QSTRIDE + cc]) = v;
        }
    }

    // k resident in 16 VGPRs
    float k[16];
    #pragma unroll
    for (int d4 = 0; d4 < 4; ++d4) {
        const float4 v = *(const float4*)(ksT + (d4 * LK + j) * 128 + bh * 4);
        k[d4 * 4 + 0] = v.x; k[d4 * 4 + 1] = v.y;
        k[d4 * 4 + 2] = v.z; k[d4 * 4 + 3] = v.w;
    }
    __syncthreads();

    #pragma unroll 4
    for (int ii = 0; ii < IT; ++ii) {
        const float* qrow = &qt[(ii * 32 + bh) * QSTRIDE];
        float q[16];
        #pragma unroll
        for (int d4 = 0; d4 < 4; ++d4) {
            const float4 v = *(const float4*)(qrow + d4 * 4);
            q[d4 * 4 + 0] = v.x; q[d4 * 4 + 1] = v.y;
            q[d4 * 4 + 2] = v.z; q[d4 * 4 + 3] = v.w;
        }
        float pn0 = 1.f, pd0 = 1.f, pn1 = 1.f, pd1 = 1.f;
        #pragma unroll
        for (int d = 0; d < 16; ++d) {
            const float u2 = fmaxf(__builtin_fabsf(q[d] - k[d]), EPS);
            const float s = __builtin_amdgcn_sinf(u2);   // sin(2pi*u2)
            if (d < 8) { pn0 *= s; pd0 *= u2; }
            else       { pn1 *= s; pd1 *= u2; }
        }
        const float r0 = pn0 * __builtin_amdgcn_rcpf(pd0);
        const float r1 = pn1 * __builtin_amdgcn_rcpf(pd1);
        out[((i0 + ii) * LK + j) * 32 + bh] = __builtin_fabsf(r0 * r1) * C16;
    }
}

extern "C" void kernel_launch(void* const* d_in, const int* in_sizes, int n_in,
                              void* d_out, int out_size, void* d_ws, size_t ws_size,
                              hipStream_t stream) {
    const float* hh     = (const float*)d_in[0];
    const float* mems   = (const float*)d_in[1];
    const float* Wq     = (const float*)d_in[2];
    const float* Wk     = (const float*)d_in[3];
    const float* paramR = (const float*)d_in[4];
    float* out = (float*)d_out;

    float* qs  = (float*)d_ws;                // 131072 floats
    float* ksT = qs + LQ * BB * DM;           // 262144 floats

    proj_kernel<<<1536, 128, 0, stream>>>(hh, mems, Wq, Wk, paramR, qs, ksT);
    score_kernel<<<dim3(LQ / IT, LK / 8), 256, 0, stream>>>(qs, ksT, out);
}